// Round 9
// baseline (723.222 us; speedup 1.0000x reference)
//
#include <hip/hip_runtime.h>

typedef __bf16 bf16x8 __attribute__((ext_vector_type(8)));
typedef __bf16 bf16x4 __attribute__((ext_vector_type(4)));
typedef float  floatx4 __attribute__((ext_vector_type(4)));

#define Vv 25
#define Tt 14
#define Ee 64
#define Hh 128
#define Ll 32
#define Ccc 8
#define G3 384
#define TABP 388   // 194 dwords == 2 mod 32 -> tok-gather bank class = tok mod 16
#define HP   136   // h row stride (bf16): b128 frag reads 2-way per 16-lane phase = free
#define CXP  72    // ctx row stride (bf16): [0,32)=z [32,40)=c [40,64)=zero pad

#define MFMA16(a, b, c) __builtin_amdgcn_mfma_f32_16x16x32_bf16(a, b, c, 0, 0, 0)

// ---------------------------------------------------------------------------
// Kernel A: token -> input-projection tables (f32, in ws).
//   enc_tab[v][j] = b_ih_e[j] + (j<256 ? b_hh_e[j] : 0) + emb_enc[v]·W_ih_e[j]
//   dec_tab[v][j] = emb_dec[v]·W_ih_d[j][:64]   (biases live in decoder base)
// ---------------------------------------------------------------------------
extern "C" __global__ void __launch_bounds__(256)
cvae_tables(const float* __restrict__ emb_enc, const float* __restrict__ W_ih_e,
            const float* __restrict__ b_ih_e, const float* __restrict__ b_hh_e,
            const float* __restrict__ emb_dec, const float* __restrict__ W_ih_d,
            float* __restrict__ ws)
{
    int id = blockIdx.x * 256 + threadIdx.x;
    if (id >= 2 * Vv * G3) return;
    int half = id / (Vv * G3);
    int r = id % (Vv * G3);
    int v = r / G3, j = r % G3;
    if (half == 0) {
        float acc = b_ih_e[j] + (j < 2 * Hh ? b_hh_e[j] : 0.0f);
        const float* e = emb_enc + v * Ee;
        const float* wp = W_ih_e + j * Ee;
        #pragma unroll 4
        for (int k = 0; k < Ee; k++) acc += e[k] * wp[k];
        ws[v * G3 + j] = acc;
    } else {
        float acc = 0.0f;
        const float* e = emb_dec + v * Ee;
        const float* wp = W_ih_d + j * 104;
        #pragma unroll 4
        for (int k = 0; k < Ee; k++) acc += e[k] * wp[k];
        ws[Vv * G3 + v * G3 + j] = acc;
    }
}

__device__ __forceinline__ float rcp_f(float x) { return __builtin_amdgcn_rcpf(x); }
// __expf -> v_mul + v_exp (fast path).  exp2f() (round 8) was an OCML guarded
// multi-inst path: VALU-cycles +28%, dur 479->527. Reverted.
__device__ __forceinline__ float sigm(float x)  { return rcp_f(1.0f + __expf(-x)); }
__device__ __forceinline__ float tanhg(float x) { return 1.0f - 2.0f * rcp_f(1.0f + __expf(2.0f * x)); }

// ---------------------------------------------------------------------------
// Fused CVAE forward (round-1 structure, measured 479 us) + two subtractive
// changes:
//  1. decoder vocab projection fused into the NEXT step's hf loads: the
//     separate of[] ds_read_b128s (4/wave/step) are deleted, and the scattered
//     global store moves from the pre-barrier vmcnt(0) drain window to the
//     top of the step (whole GEMM+gate phase to retire).
//  2. n-gate b_hh folded into the MFMA C-init (bh2v/bhnv): -16 VALU adds
//     per wave-step.
// LDS: 2*17408 + 19400 + 9216 + 896 = 64328 B.
// __launch_bounds__(512,2): (512,4) caps VGPR+AGPR at 128 -> scratch spill
// (round 2: FETCH 17MB -> 2.6GB). Occupancy: 192 regs/wave -> 2 waves/SIMD.
// ---------------------------------------------------------------------------
extern "C" __global__ void __launch_bounds__(512, 2)
cvae_mfma(const int* __restrict__ x, const float* __restrict__ cin,
          const float* __restrict__ eps,
          const float* __restrict__ W_hh_e, const float* __restrict__ b_hh_e,
          const float* __restrict__ W_mu, const float* __restrict__ b_mu,
          const float* __restrict__ W_lv, const float* __restrict__ b_lv,
          const float* __restrict__ W_fch, const float* __restrict__ b_fch,
          const float* __restrict__ W_ih_d, const float* __restrict__ W_hh_d,
          const float* __restrict__ b_ih_d, const float* __restrict__ b_hh_d,
          const float* __restrict__ W_out, const float* __restrict__ b_out,
          const float* __restrict__ tabs, float* __restrict__ out, int Btot)
{
    __shared__ __align__(16) __bf16 hA[64 * HP];       // 17408 B
    __shared__ __align__(16) __bf16 hB[64 * HP];       // 17408 B
    __shared__ __align__(16) __bf16 tab_s[Vv * TABP];  // 19400 B
    __shared__ __align__(16) __bf16 ctx_s[64 * CXP];   //  9216 B
    __shared__ unsigned char x_s[64 * Tt];             //   896 B

    const int tid  = threadIdx.x;
    const int w    = tid >> 6;            // wave id 0..7 (wave-uniform)
    const int lane = tid & 63;
    const int li   = lane & 15;
    const int q    = lane >> 4;           // quad 0..3
    const int b0   = blockIdx.x * 64;
    const size_t MU_OFF = (size_t)Btot * 13 * Vv;
    const size_t LV_OFF = MU_OFF + (size_t)Btot * Ll;
    const floatx4 zf = {0.f, 0.f, 0.f, 0.f};

    // ---- stage tokens + enc_tab (bf16) + c + ctx zero-pad ----
    for (int i = tid; i < 64 * Tt; i += 512)
        x_s[i] = (unsigned char)x[(size_t)b0 * Tt + i];
    for (int i = tid; i < Vv * G3; i += 512)
        tab_s[(i / G3) * TABP + (i % G3)] = (__bf16)tabs[i];
    {
        int b = tid >> 3, cc = tid & 7;
        ctx_s[b * CXP + Ll + cc] = (__bf16)cin[((size_t)b0 + b) * Ccc + cc];
        #pragma unroll
        for (int k3 = 0; k3 < 3; k3++) {
            int i = tid * 3 + k3;
            ctx_s[(i / 24) * CXP + 40 + (i % 24)] = (__bf16)0.f;
        }
    }

    // ---- encoder W_hh A-frags (stationary) + n-gate b_hh (to C-init) ----
    bf16x8 aW[3][4];
    #pragma unroll
    for (int role = 0; role < 3; role++)
        #pragma unroll
        for (int kb = 0; kb < 4; kb++) {
            const float* p = W_hh_e + (role * Hh + w * 16 + li) * Hh + kb * 32 + q * 8;
            bf16x8 f;
            #pragma unroll
            for (int jj = 0; jj < 8; jj++) f[jj] = (__bf16)p[jj];
            aW[role][kb] = f;
        }
    floatx4 bh2v;
    #pragma unroll
    for (int r = 0; r < 4; r++) bh2v[r] = b_hh_e[2 * Hh + w * 16 + q * 4 + r];

    float hreg[4][4];
    #pragma unroll
    for (int nt = 0; nt < 4; nt++)
        #pragma unroll
        for (int r = 0; r < 4; r++) hreg[nt][r] = 0.f;

    __syncthreads();

    // ================= encoder GRU: 14 steps, 1 barrier each =================
    for (int t = 0; t < Tt; t++) {
        const __bf16* rd = (t & 1) ? hB : hA;
        __bf16*       wr = (t & 1) ? hA : hB;

        floatx4 acc[3][4];
        #pragma unroll
        for (int nt = 0; nt < 4; nt++) {
            acc[0][nt] = zf; acc[1][nt] = zf; acc[2][nt] = bh2v;   // b_hh_n in C-init
        }
        if (t != 0) {                                 // h_0 == 0: skip h GEMM
            bf16x8 hf[4][4];
            #pragma unroll
            for (int nt = 0; nt < 4; nt++)
                #pragma unroll
                for (int kb = 0; kb < 4; kb++)
                    hf[nt][kb] = *(const bf16x8*)&rd[(nt * 16 + li) * HP + kb * 32 + q * 8];
            #pragma unroll
            for (int kb = 0; kb < 4; kb++)
                #pragma unroll
                for (int role = 0; role < 3; role++)
                    #pragma unroll
                    for (int nt = 0; nt < 4; nt++)
                        acc[role][nt] = MFMA16(aW[role][kb], hf[nt][kb], acc[role][nt]);
        }

        #pragma unroll
        for (int nt = 0; nt < 4; nt++) {
            int bl = nt * 16 + li;
            int tok = x_s[bl * Tt + t];
            const __bf16* tp = &tab_s[tok * TABP + w * 16 + q * 4];
            bf16x4 tR = *(const bf16x4*)(tp);
            bf16x4 tZ = *(const bf16x4*)(tp + Hh);
            bf16x4 tN = *(const bf16x4*)(tp + 2 * Hh);
            bf16x4 hv;
            #pragma unroll
            for (int r = 0; r < 4; r++) {
                float rr = sigm(acc[0][nt][r] + (float)tR[r]);     // b_ih+b_hh in table
                float zz = sigm(acc[1][nt][r] + (float)tZ[r]);
                float nn = tanhg((float)tN[r] + rr * acc[2][nt][r]);
                float h  = nn + zz * (hreg[nt][r] - nn);
                hreg[nt][r] = h;
                hv[r] = (__bf16)h;
            }
            *(bf16x4*)&wr[bl * HP + w * 16 + q * 4] = hv;
        }
        __syncthreads();                              // writes of wr visible
    }
    // h_enc(final) in hA (t=13 wrote hA)

    // ============ latent mu/lv via MFMA (+dec_tab staging overlap) ============
    {
        for (int i = tid; i < Vv * G3; i += 512)      // enc tab reads all done
            tab_s[(i / G3) * TABP + (i % G3)] = (__bf16)tabs[Vv * G3 + i];

        const int mt = w & 3;
        const int lp = mt * 8 + (li >> 1);
        const float* Wsrc = (li & 1) ? W_lv : W_mu;
        bf16x8 aM[5], aE[5];
        #pragma unroll
        for (int kb = 0; kb < 5; kb++) {
            bf16x8 f = {}, f2 = {};
            if (kb < 4 || q == 0) {                   // kb==4: c-part (k=128..135), q==0 lanes
                const float* p = Wsrc + lp * 136 + (kb < 4 ? kb * 32 + q * 8 : 128);
                #pragma unroll
                for (int jj = 0; jj < 8; jj++) {
                    float v = p[jj];
                    __bf16 hi = (__bf16)v;
                    f[jj]  = hi;
                    f2[jj] = (__bf16)(v - (float)hi); // residual -> f32-level precision
                }
            }
            aM[kb] = f; aE[kb] = f2;
        }
        #pragma unroll
        for (int jn = 0; jn < 2; jn++) {
            const int nt = (w >> 2) * 2 + jn;         // waves 0-3: nt 0,1; waves 4-7: nt 2,3
            floatx4 acc = zf;
            #pragma unroll
            for (int kb = 0; kb < 4; kb++) {
                bf16x8 hf = *(const bf16x8*)&hA[(nt * 16 + li) * HP + kb * 32 + q * 8];
                acc = MFMA16(aM[kb], hf, acc);
                acc = MFMA16(aE[kb], hf, acc);
            }
            {
                bf16x8 cf = {};
                if (q == 0) cf = *(const bf16x8*)&ctx_s[(nt * 16 + li) * CXP + Ll];
                acc = MFMA16(aM[4], cf, acc);
                acc = MFMA16(aE[4], cf, acc);
            }
            const int b = nt * 16 + li;
            const size_t bg = (size_t)b0 + b;
            const int l0 = mt * 8 + q * 2;
            float mu0 = acc[0] + b_mu[l0],     lv0 = acc[1] + b_lv[l0];
            float mu1 = acc[2] + b_mu[l0 + 1], lv1 = acc[3] + b_lv[l0 + 1];
            float2 ev = *(const float2*)&eps[bg * Ll + l0];
            float z0 = mu0 + ev.x * __expf(0.5f * lv0);
            float z1 = mu1 + ev.y * __expf(0.5f * lv1);
            ctx_s[b * CXP + l0]     = (__bf16)z0;
            ctx_s[b * CXP + l0 + 1] = (__bf16)z1;
            *(float2*)&out[MU_OFF + bg * Ll + l0] = make_float2(mu0, mu1);
            *(float2*)&out[LV_OFF + bg * Ll + l0] = make_float2(lv0, lv1);
        }
    }
    __syncthreads();   // B1: z in ctx_s + dec_tab visible; hA reads done

    // ======= h0 GEMM + decoder t-invariant base GEMM (shared ctx frags) =====
    floatx4 h0a[4] = {zf, zf, zf, zf};
    floatx4 base[3][4];
    #pragma unroll
    for (int role = 0; role < 3; role++)
        #pragma unroll
        for (int nt = 0; nt < 4; nt++) base[role][nt] = zf;
    #pragma unroll
    for (int kb2 = 0; kb2 < 2; kb2++) {
        bf16x8 afh, aC0, aC1, aC2;
        #pragma unroll
        for (int jj = 0; jj < 8; jj++) {
            int k = kb2 * 32 + q * 8 + jj;            // ctx k (0..63); valid < 40
            bool ok = (k < 40);
            afh[jj] = ok ? (__bf16)W_fch[(w * 16 + li) * 40 + k]                   : (__bf16)0.f;
            aC0[jj] = ok ? (__bf16)W_ih_d[(0 * Hh + w * 16 + li) * 104 + Ee + k]   : (__bf16)0.f;
            aC1[jj] = ok ? (__bf16)W_ih_d[(1 * Hh + w * 16 + li) * 104 + Ee + k]   : (__bf16)0.f;
            aC2[jj] = ok ? (__bf16)W_ih_d[(2 * Hh + w * 16 + li) * 104 + Ee + k]   : (__bf16)0.f;
        }
        #pragma unroll
        for (int nt = 0; nt < 4; nt++) {
            bf16x8 cf = *(const bf16x8*)&ctx_s[(nt * 16 + li) * CXP + kb2 * 32 + q * 8];
            h0a[nt]     = MFMA16(afh, cf, h0a[nt]);
            base[0][nt] = MFMA16(aC0, cf, base[0][nt]);
            base[1][nt] = MFMA16(aC1, cf, base[1][nt]);
            base[2][nt] = MFMA16(aC2, cf, base[2][nt]);
        }
    }
    // h0 epilogue: C layout == hreg layout -> no LDS round-trip for registers
    #pragma unroll
    for (int nt = 0; nt < 4; nt++) {
        bf16x4 hv;
        #pragma unroll
        for (int r = 0; r < 4; r++) {
            float s = h0a[nt][r] + b_fch[w * 16 + q * 4 + r];
            hreg[nt][r] = s;
            hv[r] = (__bf16)s;
        }
        *(bf16x4*)&hA[(nt * 16 + li) * HP + w * 16 + q * 4] = hv;
    }
    // fold decoder biases into base; b_hh_n -> C-init vector
    floatx4 bhnv;
    #pragma unroll
    for (int r = 0; r < 4; r++) {
        int j = w * 16 + q * 4 + r;
        float br = b_ih_d[j] + b_hh_d[j];
        float bz = b_ih_d[Hh + j] + b_hh_d[Hh + j];
        float bi = b_ih_d[2 * Hh + j];
        #pragma unroll
        for (int nt = 0; nt < 4; nt++) {
            base[0][nt][r] += br;
            base[1][nt][r] += bz;
            base[2][nt][r] += bi;
        }
        bhnv[r] = b_hh_d[2 * Hh + j];
    }
    // decoder W_hh A-frags
    #pragma unroll
    for (int role = 0; role < 3; role++)
        #pragma unroll
        for (int kb = 0; kb < 4; kb++) {
            const float* p = W_hh_d + (role * Hh + w * 16 + li) * Hh + kb * 32 + q * 8;
            bf16x8 f;
            #pragma unroll
            for (int jj = 0; jj < 8; jj++) f[jj] = (__bf16)p[jj];
            aW[role][kb] = f;
        }
    // W_out frags: wave w -> tile (mt_o = w&1, nt_o = w>>1)
    const int mt_o = w & 1, nt_o = w >> 1;
    bf16x8 aO[4];
    #pragma unroll
    for (int kb = 0; kb < 4; kb++) {
        int row = mt_o * 16 + li;
        bf16x8 f;
        #pragma unroll
        for (int jj = 0; jj < 8; jj++)
            f[jj] = (row < Vv) ? (__bf16)W_out[row * Hh + kb * 32 + q * 8 + jj] : (__bf16)0.f;
        aO[kb] = f;
    }
    float bo[4];
    #pragma unroll
    for (int r = 0; r < 4; r++) {
        int v = mt_o * 16 + q * 4 + r;
        bo[r] = (v < Vv) ? b_out[v] : 0.f;
    }

    __syncthreads();   // B2: h0 in hA visible

    // ========== decoder GRU: 13 steps, 1 barrier each ========================
    // Vocab projection for step t-1 computed at the TOP of step t from the
    // just-loaded hf (rdb == h after step t-1): no separate of[] reads, and
    // the scattered store retires during this step's GEMM+gate phase instead
    // of the pre-barrier drain. Final step's output handled after the loop.
    for (int t = 0; t < Tt - 1; t++) {
        const __bf16* rdb = (t & 1) ? hB : hA;
        __bf16*       wrb = (t & 1) ? hA : hB;

        bf16x8 hf[4][4];
        #pragma unroll
        for (int nt = 0; nt < 4; nt++)
            #pragma unroll
            for (int kb = 0; kb < 4; kb++)
                hf[nt][kb] = *(const bf16x8*)&rdb[(nt * 16 + li) * HP + kb * 32 + q * 8];

        if (t > 0) {                                  // output for step t-1
            floatx4 po = zf;
            #pragma unroll
            for (int kb = 0; kb < 4; kb++)
                po = MFMA16(aO[kb], hf[nt_o][kb], po);
            #pragma unroll
            for (int r = 0; r < 4; r++) {
                int v = mt_o * 16 + q * 4 + r;
                if (v < Vv)
                    out[((size_t)(b0 + nt_o * 16 + li) * 13 + (t - 1)) * Vv + v] = po[r] + bo[r];
            }
        }

        floatx4 acc[3][4];
        #pragma unroll
        for (int nt = 0; nt < 4; nt++) {
            acc[0][nt] = base[0][nt];
            acc[1][nt] = base[1][nt];
            acc[2][nt] = bhnv;                        // h·W_n + b_hh_n (scaled by r)
        }
        #pragma unroll
        for (int kb = 0; kb < 4; kb++)
            #pragma unroll
            for (int role = 0; role < 3; role++)
                #pragma unroll
                for (int nt = 0; nt < 4; nt++)
                    acc[role][nt] = MFMA16(aW[role][kb], hf[nt][kb], acc[role][nt]);

        #pragma unroll
        for (int nt = 0; nt < 4; nt++) {
            int bl = nt * 16 + li;
            int tok = x_s[bl * Tt + t];               // dec_in = x[:, :-1]
            const __bf16* tp = &tab_s[tok * TABP + w * 16 + q * 4];
            bf16x4 tR = *(const bf16x4*)(tp);
            bf16x4 tZ = *(const bf16x4*)(tp + Hh);
            bf16x4 tN = *(const bf16x4*)(tp + 2 * Hh);
            bf16x4 hv;
            #pragma unroll
            for (int r = 0; r < 4; r++) {
                float rr = sigm(acc[0][nt][r] + (float)tR[r]);
                float zz = sigm(acc[1][nt][r] + (float)tZ[r]);
                float nn = tanhg(base[2][nt][r] + (float)tN[r] + rr * acc[2][nt][r]);
                float h  = nn + zz * (hreg[nt][r] - nn);
                hreg[nt][r] = h;
                hv[r] = (__bf16)h;
            }
            *(bf16x4*)&wrb[bl * HP + w * 16 + q * 4] = hv;
        }
        __syncthreads();                              // h_new (wrb) visible
    }
    // final vocab projection: state after last step is in wrb of t=Tt-2
    {
        const __bf16* fin = ((Tt - 2) & 1) ? hA : hB;
        bf16x8 of[4];
        #pragma unroll
        for (int kb = 0; kb < 4; kb++)
            of[kb] = *(const bf16x8*)&fin[(nt_o * 16 + li) * HP + kb * 32 + q * 8];
        floatx4 po = zf;
        #pragma unroll
        for (int kb = 0; kb < 4; kb++)
            po = MFMA16(aO[kb], of[kb], po);
        #pragma unroll
        for (int r = 0; r < 4; r++) {
            int v = mt_o * 16 + q * 4 + r;
            if (v < Vv)
                out[((size_t)(b0 + nt_o * 16 + li) * 13 + (Tt - 2)) * Vv + v] = po[r] + bo[r];
        }
    }
}

extern "C" void kernel_launch(void* const* d_in, const int* in_sizes, int n_in,
                              void* d_out, int out_size, void* d_ws, size_t ws_size,
                              hipStream_t stream)
{
    const int*   x       = (const int*)d_in[0];
    const float* c       = (const float*)d_in[1];
    const float* eps     = (const float*)d_in[2];
    const float* emb_enc = (const float*)d_in[3];
    const float* W_ih_e  = (const float*)d_in[4];
    const float* W_hh_e  = (const float*)d_in[5];
    const float* b_ih_e  = (const float*)d_in[6];
    const float* b_hh_e  = (const float*)d_in[7];
    const float* W_mu    = (const float*)d_in[8];
    const float* b_mu    = (const float*)d_in[9];
    const float* W_lv    = (const float*)d_in[10];
    const float* b_lv    = (const float*)d_in[11];
    const float* emb_dec = (const float*)d_in[12];
    const float* W_fch   = (const float*)d_in[13];
    const float* b_fch   = (const float*)d_in[14];
    const float* W_ih_d  = (const float*)d_in[15];
    const float* W_hh_d  = (const float*)d_in[16];
    const float* b_ih_d  = (const float*)d_in[17];
    const float* b_hh_d  = (const float*)d_in[18];
    const float* W_out   = (const float*)d_in[19];
    const float* b_out   = (const float*)d_in[20];

    float* ws = (float*)d_ws;
    const int Btot = in_sizes[0] / Tt;

    cvae_tables<<<75, 256, 0, stream>>>(emb_enc, W_ih_e, b_ih_e, b_hh_e, emb_dec, W_ih_d, ws);

    cvae_mfma<<<Btot / 64, 512, 0, stream>>>(
        x, c, eps, W_hh_e, b_hh_e, W_mu, b_mu, W_lv, b_lv,
        W_fch, b_fch, W_ih_d, W_hh_d, b_ih_d, b_hh_d, W_out, b_out,
        ws, (float*)d_out, Btot);
}

// Round 10
// 546.024 us; speedup vs baseline: 1.3245x; 1.3245x over previous
//
#include <hip/hip_runtime.h>

typedef __bf16 bf16x8 __attribute__((ext_vector_type(8)));
typedef __bf16 bf16x4 __attribute__((ext_vector_type(4)));
typedef float  floatx4 __attribute__((ext_vector_type(4)));

#define Vv 25
#define Tt 14
#define Ee 64
#define Hh 128
#define Ll 32
#define Ccc 8
#define G3 384
#define TABP 388   // 194 dwords == 2 mod 32 -> tok-gather bank class = tok mod 16
#define HP   136   // h row stride (bf16): b128 frag reads 2-way per 16-lane phase = free
#define CXP  72    // ctx row stride (bf16): [0,32)=z [32,40)=c [40,64)=zero pad

#define MFMA16(a, b, c) __builtin_amdgcn_mfma_f32_16x16x32_bf16(a, b, c, 0, 0, 0)

// ---------------------------------------------------------------------------
// Kernel A: token -> input-projection tables (f32, in ws).
//   enc_tab[v][j] = b_ih_e[j] + (j<256 ? b_hh_e[j] : 0) + emb_enc[v]·W_ih_e[j]
//   dec_tab[v][j] = emb_dec[v]·W_ih_d[j][:64]   (biases live in decoder base)
// ---------------------------------------------------------------------------
extern "C" __global__ void __launch_bounds__(256)
cvae_tables(const float* __restrict__ emb_enc, const float* __restrict__ W_ih_e,
            const float* __restrict__ b_ih_e, const float* __restrict__ b_hh_e,
            const float* __restrict__ emb_dec, const float* __restrict__ W_ih_d,
            float* __restrict__ ws)
{
    int id = blockIdx.x * 256 + threadIdx.x;
    if (id >= 2 * Vv * G3) return;
    int half = id / (Vv * G3);
    int r = id % (Vv * G3);
    int v = r / G3, j = r % G3;
    if (half == 0) {
        float acc = b_ih_e[j] + (j < 2 * Hh ? b_hh_e[j] : 0.0f);
        const float* e = emb_enc + v * Ee;
        const float* wp = W_ih_e + j * Ee;
        #pragma unroll 4
        for (int k = 0; k < Ee; k++) acc += e[k] * wp[k];
        ws[v * G3 + j] = acc;
    } else {
        float acc = 0.0f;
        const float* e = emb_dec + v * Ee;
        const float* wp = W_ih_d + j * 104;
        #pragma unroll 4
        for (int k = 0; k < Ee; k++) acc += e[k] * wp[k];
        ws[Vv * G3 + v * G3 + j] = acc;
    }
}

__device__ __forceinline__ float rcp_f(float x) { return __builtin_amdgcn_rcpf(x); }
// __expf -> v_mul + v_exp. (exp2f/OCML guarded path cost +28% VALU — round 8.)
__device__ __forceinline__ float sigm(float x)  { return rcp_f(1.0f + __expf(-x)); }
__device__ __forceinline__ float tanhg(float x) { return 1.0f - 2.0f * rcp_f(1.0f + __expf(2.0f * x)); }

// ---------------------------------------------------------------------------
// Fused CVAE forward — round-1 structure (measured 479 us, session best).
// Only two strictly-subtractive deltas vs round 1:
//  1. n-gate b_hh folded into MFMA C-init (bh2v/bhnv): -16 VALU adds/wave-step.
//  2. vocab store as one 16B memcpy (compiler -> global_store_dwordx4 or the
//     identical 4 dwords): stores can never be scheduler-split. Placement
//     UNCHANGED (end of step, after barrier): round 9 proved early issue
//     breaks store merging (WRITE 118MB -> 1.83GB, +160us); round 3/4 proved
//     LDS staging is also a loss. Baseline placement is optimal.
// LDS: 2*17408 + 19400 + 9216 + 896 = 64328 B.
// __launch_bounds__(512,2): (512,4) caps VGPR+AGPR at 128 -> scratch spill
// (round 2: FETCH 17MB->2.6GB). 192 regs/wave -> 2 waves/SIMD, 1 block/CU —
// the occupancy ceiling for this register footprint (m69: halving at 128/256).
// ---------------------------------------------------------------------------
extern "C" __global__ void __launch_bounds__(512, 2)
cvae_mfma(const int* __restrict__ x, const float* __restrict__ cin,
          const float* __restrict__ eps,
          const float* __restrict__ W_hh_e, const float* __restrict__ b_hh_e,
          const float* __restrict__ W_mu, const float* __restrict__ b_mu,
          const float* __restrict__ W_lv, const float* __restrict__ b_lv,
          const float* __restrict__ W_fch, const float* __restrict__ b_fch,
          const float* __restrict__ W_ih_d, const float* __restrict__ W_hh_d,
          const float* __restrict__ b_ih_d, const float* __restrict__ b_hh_d,
          const float* __restrict__ W_out, const float* __restrict__ b_out,
          const float* __restrict__ tabs, float* __restrict__ out, int Btot)
{
    __shared__ __align__(16) __bf16 hA[64 * HP];       // 17408 B
    __shared__ __align__(16) __bf16 hB[64 * HP];       // 17408 B
    __shared__ __align__(16) __bf16 tab_s[Vv * TABP];  // 19400 B
    __shared__ __align__(16) __bf16 ctx_s[64 * CXP];   //  9216 B
    __shared__ unsigned char x_s[64 * Tt];             //   896 B

    const int tid  = threadIdx.x;
    const int w    = tid >> 6;            // wave id 0..7 (wave-uniform)
    const int lane = tid & 63;
    const int li   = lane & 15;
    const int q    = lane >> 4;           // quad 0..3
    const int b0   = blockIdx.x * 64;
    const size_t MU_OFF = (size_t)Btot * 13 * Vv;
    const size_t LV_OFF = MU_OFF + (size_t)Btot * Ll;
    const floatx4 zf = {0.f, 0.f, 0.f, 0.f};

    // ---- stage tokens + enc_tab (bf16) + c + ctx zero-pad ----
    for (int i = tid; i < 64 * Tt; i += 512)
        x_s[i] = (unsigned char)x[(size_t)b0 * Tt + i];
    for (int i = tid; i < Vv * G3; i += 512)
        tab_s[(i / G3) * TABP + (i % G3)] = (__bf16)tabs[i];
    {
        int b = tid >> 3, cc = tid & 7;
        ctx_s[b * CXP + Ll + cc] = (__bf16)cin[((size_t)b0 + b) * Ccc + cc];
        #pragma unroll
        for (int k3 = 0; k3 < 3; k3++) {
            int i = tid * 3 + k3;
            ctx_s[(i / 24) * CXP + 40 + (i % 24)] = (__bf16)0.f;
        }
    }

    // ---- encoder W_hh A-frags (stationary) + n-gate b_hh (to C-init) ----
    bf16x8 aW[3][4];
    #pragma unroll
    for (int role = 0; role < 3; role++)
        #pragma unroll
        for (int kb = 0; kb < 4; kb++) {
            const float* p = W_hh_e + (role * Hh + w * 16 + li) * Hh + kb * 32 + q * 8;
            bf16x8 f;
            #pragma unroll
            for (int jj = 0; jj < 8; jj++) f[jj] = (__bf16)p[jj];
            aW[role][kb] = f;
        }
    floatx4 bh2v;
    #pragma unroll
    for (int r = 0; r < 4; r++) bh2v[r] = b_hh_e[2 * Hh + w * 16 + q * 4 + r];

    float hreg[4][4];
    #pragma unroll
    for (int nt = 0; nt < 4; nt++)
        #pragma unroll
        for (int r = 0; r < 4; r++) hreg[nt][r] = 0.f;

    __syncthreads();

    // ================= encoder GRU: 14 steps, 1 barrier each =================
    for (int t = 0; t < Tt; t++) {
        const __bf16* rd = (t & 1) ? hB : hA;
        __bf16*       wr = (t & 1) ? hA : hB;

        floatx4 acc[3][4];
        #pragma unroll
        for (int nt = 0; nt < 4; nt++) {
            acc[0][nt] = zf; acc[1][nt] = zf; acc[2][nt] = bh2v;   // b_hh_n in C-init
        }
        if (t != 0) {                                 // h_0 == 0: skip h GEMM
            bf16x8 hf[4][4];
            #pragma unroll
            for (int nt = 0; nt < 4; nt++)
                #pragma unroll
                for (int kb = 0; kb < 4; kb++)
                    hf[nt][kb] = *(const bf16x8*)&rd[(nt * 16 + li) * HP + kb * 32 + q * 8];
            #pragma unroll
            for (int kb = 0; kb < 4; kb++)
                #pragma unroll
                for (int role = 0; role < 3; role++)
                    #pragma unroll
                    for (int nt = 0; nt < 4; nt++)
                        acc[role][nt] = MFMA16(aW[role][kb], hf[nt][kb], acc[role][nt]);
        }

        #pragma unroll
        for (int nt = 0; nt < 4; nt++) {
            int bl = nt * 16 + li;
            int tok = x_s[bl * Tt + t];
            const __bf16* tp = &tab_s[tok * TABP + w * 16 + q * 4];
            bf16x4 tR = *(const bf16x4*)(tp);
            bf16x4 tZ = *(const bf16x4*)(tp + Hh);
            bf16x4 tN = *(const bf16x4*)(tp + 2 * Hh);
            bf16x4 hv;
            #pragma unroll
            for (int r = 0; r < 4; r++) {
                float rr = sigm(acc[0][nt][r] + (float)tR[r]);     // b_ih+b_hh in table
                float zz = sigm(acc[1][nt][r] + (float)tZ[r]);
                float nn = tanhg((float)tN[r] + rr * acc[2][nt][r]);
                float h  = nn + zz * (hreg[nt][r] - nn);
                hreg[nt][r] = h;
                hv[r] = (__bf16)h;
            }
            *(bf16x4*)&wr[bl * HP + w * 16 + q * 4] = hv;
        }
        __syncthreads();                              // writes of wr visible
    }
    // h_enc(final) in hA (t=13 wrote hA)

    // ============ latent mu/lv via MFMA (+dec_tab staging overlap) ============
    {
        for (int i = tid; i < Vv * G3; i += 512)      // enc tab reads all done
            tab_s[(i / G3) * TABP + (i % G3)] = (__bf16)tabs[Vv * G3 + i];

        const int mt = w & 3;
        const int lp = mt * 8 + (li >> 1);
        const float* Wsrc = (li & 1) ? W_lv : W_mu;
        bf16x8 aM[5], aE[5];
        #pragma unroll
        for (int kb = 0; kb < 5; kb++) {
            bf16x8 f = {}, f2 = {};
            if (kb < 4 || q == 0) {                   // kb==4: c-part (k=128..135), q==0 lanes
                const float* p = Wsrc + lp * 136 + (kb < 4 ? kb * 32 + q * 8 : 128);
                #pragma unroll
                for (int jj = 0; jj < 8; jj++) {
                    float v = p[jj];
                    __bf16 hi = (__bf16)v;
                    f[jj]  = hi;
                    f2[jj] = (__bf16)(v - (float)hi); // residual -> f32-level precision
                }
            }
            aM[kb] = f; aE[kb] = f2;
        }
        #pragma unroll
        for (int jn = 0; jn < 2; jn++) {
            const int nt = (w >> 2) * 2 + jn;         // waves 0-3: nt 0,1; waves 4-7: nt 2,3
            floatx4 acc = zf;
            #pragma unroll
            for (int kb = 0; kb < 4; kb++) {
                bf16x8 hf = *(const bf16x8*)&hA[(nt * 16 + li) * HP + kb * 32 + q * 8];
                acc = MFMA16(aM[kb], hf, acc);
                acc = MFMA16(aE[kb], hf, acc);
            }
            {
                bf16x8 cf = {};
                if (q == 0) cf = *(const bf16x8*)&ctx_s[(nt * 16 + li) * CXP + Ll];
                acc = MFMA16(aM[4], cf, acc);
                acc = MFMA16(aE[4], cf, acc);
            }
            const int b = nt * 16 + li;
            const size_t bg = (size_t)b0 + b;
            const int l0 = mt * 8 + q * 2;
            float mu0 = acc[0] + b_mu[l0],     lv0 = acc[1] + b_lv[l0];
            float mu1 = acc[2] + b_mu[l0 + 1], lv1 = acc[3] + b_lv[l0 + 1];
            float2 ev = *(const float2*)&eps[bg * Ll + l0];
            float z0 = mu0 + ev.x * __expf(0.5f * lv0);
            float z1 = mu1 + ev.y * __expf(0.5f * lv1);
            ctx_s[b * CXP + l0]     = (__bf16)z0;
            ctx_s[b * CXP + l0 + 1] = (__bf16)z1;
            *(float2*)&out[MU_OFF + bg * Ll + l0] = make_float2(mu0, mu1);
            *(float2*)&out[LV_OFF + bg * Ll + l0] = make_float2(lv0, lv1);
        }
    }
    __syncthreads();   // B1: z in ctx_s + dec_tab visible; hA reads done

    // ======= h0 GEMM + decoder t-invariant base GEMM (shared ctx frags) =====
    floatx4 h0a[4] = {zf, zf, zf, zf};
    floatx4 base[3][4];
    #pragma unroll
    for (int role = 0; role < 3; role++)
        #pragma unroll
        for (int nt = 0; nt < 4; nt++) base[role][nt] = zf;
    #pragma unroll
    for (int kb2 = 0; kb2 < 2; kb2++) {
        bf16x8 afh, aC0, aC1, aC2;
        #pragma unroll
        for (int jj = 0; jj < 8; jj++) {
            int k = kb2 * 32 + q * 8 + jj;            // ctx k (0..63); valid < 40
            bool ok = (k < 40);
            afh[jj] = ok ? (__bf16)W_fch[(w * 16 + li) * 40 + k]                   : (__bf16)0.f;
            aC0[jj] = ok ? (__bf16)W_ih_d[(0 * Hh + w * 16 + li) * 104 + Ee + k]   : (__bf16)0.f;
            aC1[jj] = ok ? (__bf16)W_ih_d[(1 * Hh + w * 16 + li) * 104 + Ee + k]   : (__bf16)0.f;
            aC2[jj] = ok ? (__bf16)W_ih_d[(2 * Hh + w * 16 + li) * 104 + Ee + k]   : (__bf16)0.f;
        }
        #pragma unroll
        for (int nt = 0; nt < 4; nt++) {
            bf16x8 cf = *(const bf16x8*)&ctx_s[(nt * 16 + li) * CXP + kb2 * 32 + q * 8];
            h0a[nt]     = MFMA16(afh, cf, h0a[nt]);
            base[0][nt] = MFMA16(aC0, cf, base[0][nt]);
            base[1][nt] = MFMA16(aC1, cf, base[1][nt]);
            base[2][nt] = MFMA16(aC2, cf, base[2][nt]);
        }
    }
    // h0 epilogue: C layout == hreg layout -> no LDS round-trip for registers
    #pragma unroll
    for (int nt = 0; nt < 4; nt++) {
        bf16x4 hv;
        #pragma unroll
        for (int r = 0; r < 4; r++) {
            float s = h0a[nt][r] + b_fch[w * 16 + q * 4 + r];
            hreg[nt][r] = s;
            hv[r] = (__bf16)s;
        }
        *(bf16x4*)&hA[(nt * 16 + li) * HP + w * 16 + q * 4] = hv;
    }
    // fold decoder biases into base; b_hh_n -> C-init vector
    floatx4 bhnv;
    #pragma unroll
    for (int r = 0; r < 4; r++) {
        int j = w * 16 + q * 4 + r;
        float br = b_ih_d[j] + b_hh_d[j];
        float bz = b_ih_d[Hh + j] + b_hh_d[Hh + j];
        float bi = b_ih_d[2 * Hh + j];
        #pragma unroll
        for (int nt = 0; nt < 4; nt++) {
            base[0][nt][r] += br;
            base[1][nt][r] += bz;
            base[2][nt][r] += bi;
        }
        bhnv[r] = b_hh_d[2 * Hh + j];
    }
    // decoder W_hh A-frags
    #pragma unroll
    for (int role = 0; role < 3; role++)
        #pragma unroll
        for (int kb = 0; kb < 4; kb++) {
            const float* p = W_hh_d + (role * Hh + w * 16 + li) * Hh + kb * 32 + q * 8;
            bf16x8 f;
            #pragma unroll
            for (int jj = 0; jj < 8; jj++) f[jj] = (__bf16)p[jj];
            aW[role][kb] = f;
        }
    // W_out frags: wave w -> tile (mt_o = w&1, nt_o = w>>1)
    const int mt_o = w & 1, nt_o = w >> 1;
    bf16x8 aO[4];
    #pragma unroll
    for (int kb = 0; kb < 4; kb++) {
        int row = mt_o * 16 + li;
        bf16x8 f;
        #pragma unroll
        for (int jj = 0; jj < 8; jj++)
            f[jj] = (row < Vv) ? (__bf16)W_out[row * Hh + kb * 32 + q * 8 + jj] : (__bf16)0.f;
        aO[kb] = f;
    }
    float bo[4];
    #pragma unroll
    for (int r = 0; r < 4; r++) {
        int v = mt_o * 16 + q * 4 + r;
        bo[r] = (v < Vv) ? b_out[v] : 0.f;
    }

    __syncthreads();   // B2: h0 in hA visible

    // ========== decoder GRU: 13 steps, 1 barrier each + fused vocab proj ====
    for (int t = 0; t < Tt - 1; t++) {
        const __bf16* rdb = (t & 1) ? hB : hA;
        __bf16*       wrb = (t & 1) ? hA : hB;

        floatx4 acc[3][4];
        #pragma unroll
        for (int nt = 0; nt < 4; nt++) {
            acc[0][nt] = base[0][nt];
            acc[1][nt] = base[1][nt];
            acc[2][nt] = bhnv;                        // h·W_n + b_hh_n (scaled by r)
        }

        bf16x8 hf[4][4];
        #pragma unroll
        for (int nt = 0; nt < 4; nt++)
            #pragma unroll
            for (int kb = 0; kb < 4; kb++)
                hf[nt][kb] = *(const bf16x8*)&rdb[(nt * 16 + li) * HP + kb * 32 + q * 8];
        #pragma unroll
        for (int kb = 0; kb < 4; kb++)
            #pragma unroll
            for (int role = 0; role < 3; role++)
                #pragma unroll
                for (int nt = 0; nt < 4; nt++)
                    acc[role][nt] = MFMA16(aW[role][kb], hf[nt][kb], acc[role][nt]);

        #pragma unroll
        for (int nt = 0; nt < 4; nt++) {
            int bl = nt * 16 + li;
            int tok = x_s[bl * Tt + t];               // dec_in = x[:, :-1]
            const __bf16* tp = &tab_s[tok * TABP + w * 16 + q * 4];
            bf16x4 tR = *(const bf16x4*)(tp);
            bf16x4 tZ = *(const bf16x4*)(tp + Hh);
            bf16x4 tN = *(const bf16x4*)(tp + 2 * Hh);
            bf16x4 hv;
            #pragma unroll
            for (int r = 0; r < 4; r++) {
                float rr = sigm(acc[0][nt][r] + (float)tR[r]);
                float zz = sigm(acc[1][nt][r] + (float)tZ[r]);
                float nn = tanhg(base[2][nt][r] + (float)tN[r] + rr * acc[2][nt][r]);
                float h  = nn + zz * (hreg[nt][r] - nn);
                hreg[nt][r] = h;
                hv[r] = (__bf16)h;
            }
            *(bf16x4*)&wrb[bl * HP + w * 16 + q * 4] = hv;
        }
        __syncthreads();                              // h_new (wrb) visible

        // vocab projection: one 16x16 tile per wave, reads wrb (= h after step t)
        bf16x8 of[4];
        #pragma unroll
        for (int kb = 0; kb < 4; kb++)
            of[kb] = *(const bf16x8*)&wrb[(nt_o * 16 + li) * HP + kb * 32 + q * 8];
        floatx4 po = zf;
        #pragma unroll
        for (int kb = 0; kb < 4; kb++)
            po = MFMA16(aO[kb], of[kb], po);
        {
            int vbase = mt_o * 16 + q * 4;
            floatx4 pv;
            #pragma unroll
            for (int r = 0; r < 4; r++) pv[r] = po[r] + bo[r];
            float* op = &out[((size_t)(b0 + nt_o * 16 + li) * 13 + t) * Vv + vbase];
            if (vbase + 4 <= Vv)      __builtin_memcpy(op, &pv, 16);  // single 16B store
            else if (vbase < Vv)      op[0] = pv[0];                  // vbase 24: v=24 only
        }
    }
}

extern "C" void kernel_launch(void* const* d_in, const int* in_sizes, int n_in,
                              void* d_out, int out_size, void* d_ws, size_t ws_size,
                              hipStream_t stream)
{
    const int*   x       = (const int*)d_in[0];
    const float* c       = (const float*)d_in[1];
    const float* eps     = (const float*)d_in[2];
    const float* emb_enc = (const float*)d_in[3];
    const float* W_ih_e  = (const float*)d_in[4];
    const float* W_hh_e  = (const float*)d_in[5];
    const float* b_ih_e  = (const float*)d_in[6];
    const float* b_hh_e  = (const float*)d_in[7];
    const float* W_mu    = (const float*)d_in[8];
    const float* b_mu    = (const float*)d_in[9];
    const float* W_lv    = (const float*)d_in[10];
    const float* b_lv    = (const float*)d_in[11];
    const float* emb_dec = (const float*)d_in[12];
    const float* W_fch   = (const float*)d_in[13];
    const float* b_fch   = (const float*)d_in[14];
    const float* W_ih_d  = (const float*)d_in[15];
    const float* W_hh_d  = (const float*)d_in[16];
    const float* b_ih_d  = (const float*)d_in[17];
    const float* b_hh_d  = (const float*)d_in[18];
    const float* W_out   = (const float*)d_in[19];
    const float* b_out   = (const float*)d_in[20];

    float* ws = (float*)d_ws;
    const int Btot = in_sizes[0] / Tt;

    cvae_tables<<<75, 256, 0, stream>>>(emb_enc, W_ih_e, b_ih_e, b_hh_e, emb_dec, W_ih_d, ws);

    cvae_mfma<<<Btot / 64, 512, 0, stream>>>(
        x, c, eps, W_hh_e, b_hh_e, W_mu, b_mu, W_lv, b_lv,
        W_fch, b_fch, W_ih_d, W_hh_d, b_ih_d, b_hh_d, W_out, b_out,
        ws, (float*)d_out, Btot);
}

// Round 11
// 520.149 us; speedup vs baseline: 1.3904x; 1.0497x over previous
//
#include <hip/hip_runtime.h>

typedef __bf16 bf16x8 __attribute__((ext_vector_type(8)));
typedef __bf16 bf16x4 __attribute__((ext_vector_type(4)));
typedef float  floatx4 __attribute__((ext_vector_type(4)));

#define Vv 25
#define Tt 14
#define Ee 64
#define Hh 128
#define Ll 32
#define Ccc 8
#define G3 384
#define TABP 388   // 194 dwords == 2 mod 32 -> tok-gather bank class = tok mod 16
#define HP   136   // h row stride (bf16): b128 frag reads 2-way per 16-lane phase = free
#define CXP  72    // ctx row stride (bf16): [0,32)=z [32,40)=c [40,64)=zero pad

#define NLOG2E (-1.44269504088896340736f)   // r/z pre-scale: sigmoid = rcp(1+2^y)
#define TLOG2E ( 2.88539008177792681472f)   // n pre-scale:   tanh = 1-2*rcp(1+2^y)

#define MFMA16(a, b, c) __builtin_amdgcn_mfma_f32_16x16x32_bf16(a, b, c, 0, 0, 0)

// ---------------------------------------------------------------------------
// Kernel A: token -> input-projection tables (f32, in ws), PRE-SCALED:
//   enc_tab[v][j] = (b_ih_e[j] + (j<256 ? b_hh_e[j] : 0) + emb_enc[v]·W_ih_e[j]) * sc(j)
//   dec_tab[v][j] = (emb_dec[v]·W_ih_d[j][:64]) * sc(j)
//   sc(j) = -log2e (r/z rows, j<256), +2log2e (n rows). The main kernel then
//   uses bare v_exp_f32 (2^x) with no per-element log2e multiply.
// ---------------------------------------------------------------------------
extern "C" __global__ void __launch_bounds__(256)
cvae_tables(const float* __restrict__ emb_enc, const float* __restrict__ W_ih_e,
            const float* __restrict__ b_ih_e, const float* __restrict__ b_hh_e,
            const float* __restrict__ emb_dec, const float* __restrict__ W_ih_d,
            float* __restrict__ ws)
{
    int id = blockIdx.x * 256 + threadIdx.x;
    if (id >= 2 * Vv * G3) return;
    int half = id / (Vv * G3);
    int r = id % (Vv * G3);
    int v = r / G3, j = r % G3;
    float sc = (j < 2 * Hh) ? NLOG2E : TLOG2E;
    if (half == 0) {
        float acc = b_ih_e[j] + (j < 2 * Hh ? b_hh_e[j] : 0.0f);
        const float* e = emb_enc + v * Ee;
        const float* wp = W_ih_e + j * Ee;
        #pragma unroll 4
        for (int k = 0; k < Ee; k++) acc += e[k] * wp[k];
        ws[v * G3 + j] = acc * sc;
    } else {
        float acc = 0.0f;
        const float* e = emb_dec + v * Ee;
        const float* wp = W_ih_d + j * 104;
        #pragma unroll 4
        for (int k = 0; k < Ee; k++) acc += e[k] * wp[k];
        ws[Vv * G3 + v * G3 + j] = acc * sc;
    }
}

__device__ __forceinline__ float rcp_f(float x) { return __builtin_amdgcn_rcpf(x); }
// Bare HW 2^x. Round 8 showed exp2f() goes through a guarded OCML path
// (+28% VALU); a single interlocked v_exp_f32 is the intended instruction.
__device__ __forceinline__ float exp2_hw(float x)
{
    float r;
    asm("v_exp_f32 %0, %1" : "=v"(r) : "v"(x));
    return r;
}
// y pre-scaled by -log2e  -> sigmoid(x) = rcp(1 + 2^y)
__device__ __forceinline__ float sigm2(float y) { return rcp_f(1.0f + exp2_hw(y)); }
// y pre-scaled by 2*log2e -> tanh(x) = 1 - 2*rcp(1 + 2^y)
__device__ __forceinline__ float tanh2(float y) { return 1.0f - 2.0f * rcp_f(1.0f + exp2_hw(y)); }

// ---------------------------------------------------------------------------
// Fused CVAE forward — round-10 structure (measured 453 us, session best) +
// log2e folded into weights/tables with inline-asm v_exp_f32 (deletes the
// v_mul inside every __expf: 3 muls x 16 elems per wave-step).
// LDS: 2*17408 + 19400 + 9216 + 896 = 64328 B.
// __launch_bounds__(512,2): (512,4) caps VGPR+AGPR at 128 -> scratch spill
// (round 2). 188 regs/wave -> 2 waves/SIMD, 1 block/CU.
// Store path: single 16B memcpy at end-of-step after barrier — round 9 proved
// early issue splits store merging (WRITE 118MB -> 1.83GB); keep placement.
// ---------------------------------------------------------------------------
extern "C" __global__ void __launch_bounds__(512, 2)
cvae_mfma(const int* __restrict__ x, const float* __restrict__ cin,
          const float* __restrict__ eps,
          const float* __restrict__ W_hh_e, const float* __restrict__ b_hh_e,
          const float* __restrict__ W_mu, const float* __restrict__ b_mu,
          const float* __restrict__ W_lv, const float* __restrict__ b_lv,
          const float* __restrict__ W_fch, const float* __restrict__ b_fch,
          const float* __restrict__ W_ih_d, const float* __restrict__ W_hh_d,
          const float* __restrict__ b_ih_d, const float* __restrict__ b_hh_d,
          const float* __restrict__ W_out, const float* __restrict__ b_out,
          const float* __restrict__ tabs, float* __restrict__ out, int Btot)
{
    __shared__ __align__(16) __bf16 hA[64 * HP];       // 17408 B
    __shared__ __align__(16) __bf16 hB[64 * HP];       // 17408 B
    __shared__ __align__(16) __bf16 tab_s[Vv * TABP];  // 19400 B
    __shared__ __align__(16) __bf16 ctx_s[64 * CXP];   //  9216 B
    __shared__ unsigned char x_s[64 * Tt];             //   896 B

    const int tid  = threadIdx.x;
    const int w    = tid >> 6;            // wave id 0..7 (wave-uniform)
    const int lane = tid & 63;
    const int li   = lane & 15;
    const int q    = lane >> 4;           // quad 0..3
    const int b0   = blockIdx.x * 64;
    const size_t MU_OFF = (size_t)Btot * 13 * Vv;
    const size_t LV_OFF = MU_OFF + (size_t)Btot * Ll;
    const floatx4 zf = {0.f, 0.f, 0.f, 0.f};

    // ---- stage tokens + enc_tab (bf16) + c + ctx zero-pad ----
    for (int i = tid; i < 64 * Tt; i += 512)
        x_s[i] = (unsigned char)x[(size_t)b0 * Tt + i];
    for (int i = tid; i < Vv * G3; i += 512)
        tab_s[(i / G3) * TABP + (i % G3)] = (__bf16)tabs[i];
    {
        int b = tid >> 3, cc = tid & 7;
        ctx_s[b * CXP + Ll + cc] = (__bf16)cin[((size_t)b0 + b) * Ccc + cc];
        #pragma unroll
        for (int k3 = 0; k3 < 3; k3++) {
            int i = tid * 3 + k3;
            ctx_s[(i / 24) * CXP + 40 + (i % 24)] = (__bf16)0.f;
        }
    }

    // ---- encoder W_hh A-frags (stationary, PRE-SCALED) + n-gate b_hh ----
    bf16x8 aW[3][4];
    #pragma unroll
    for (int role = 0; role < 3; role++) {
        const float sc = (role < 2) ? NLOG2E : TLOG2E;
        #pragma unroll
        for (int kb = 0; kb < 4; kb++) {
            const float* p = W_hh_e + (role * Hh + w * 16 + li) * Hh + kb * 32 + q * 8;
            bf16x8 f;
            #pragma unroll
            for (int jj = 0; jj < 8; jj++) f[jj] = (__bf16)(p[jj] * sc);
            aW[role][kb] = f;
        }
    }
    floatx4 bh2v;
    #pragma unroll
    for (int r = 0; r < 4; r++) bh2v[r] = b_hh_e[2 * Hh + w * 16 + q * 4 + r] * TLOG2E;

    float hreg[4][4];
    #pragma unroll
    for (int nt = 0; nt < 4; nt++)
        #pragma unroll
        for (int r = 0; r < 4; r++) hreg[nt][r] = 0.f;

    __syncthreads();

    // ================= encoder GRU: 14 steps, 1 barrier each =================
    for (int t = 0; t < Tt; t++) {
        const __bf16* rd = (t & 1) ? hB : hA;
        __bf16*       wr = (t & 1) ? hA : hB;

        floatx4 acc[3][4];
        #pragma unroll
        for (int nt = 0; nt < 4; nt++) {
            acc[0][nt] = zf; acc[1][nt] = zf; acc[2][nt] = bh2v;   // b_hh_n in C-init
        }
        if (t != 0) {                                 // h_0 == 0: skip h GEMM
            bf16x8 hf[4][4];
            #pragma unroll
            for (int nt = 0; nt < 4; nt++)
                #pragma unroll
                for (int kb = 0; kb < 4; kb++)
                    hf[nt][kb] = *(const bf16x8*)&rd[(nt * 16 + li) * HP + kb * 32 + q * 8];
            #pragma unroll
            for (int kb = 0; kb < 4; kb++)
                #pragma unroll
                for (int role = 0; role < 3; role++)
                    #pragma unroll
                    for (int nt = 0; nt < 4; nt++)
                        acc[role][nt] = MFMA16(aW[role][kb], hf[nt][kb], acc[role][nt]);
        }

        #pragma unroll
        for (int nt = 0; nt < 4; nt++) {
            int bl = nt * 16 + li;
            int tok = x_s[bl * Tt + t];
            const __bf16* tp = &tab_s[tok * TABP + w * 16 + q * 4];
            bf16x4 tR = *(const bf16x4*)(tp);
            bf16x4 tZ = *(const bf16x4*)(tp + Hh);
            bf16x4 tN = *(const bf16x4*)(tp + 2 * Hh);
            bf16x4 hv;
            #pragma unroll
            for (int r = 0; r < 4; r++) {
                float rr = sigm2(acc[0][nt][r] + (float)tR[r]);    // all pre-scaled
                float zz = sigm2(acc[1][nt][r] + (float)tZ[r]);
                float nn = tanh2((float)tN[r] + rr * acc[2][nt][r]);
                float h  = nn + zz * (hreg[nt][r] - nn);
                hreg[nt][r] = h;
                hv[r] = (__bf16)h;
            }
            *(bf16x4*)&wr[bl * HP + w * 16 + q * 4] = hv;
        }
        __syncthreads();                              // writes of wr visible
    }
    // h_enc(final) in hA (t=13 wrote hA)

    // ============ latent mu/lv via MFMA (+dec_tab staging overlap) ============
    {
        for (int i = tid; i < Vv * G3; i += 512)      // enc tab reads all done
            tab_s[(i / G3) * TABP + (i % G3)] = (__bf16)tabs[Vv * G3 + i];

        const int mt = w & 3;
        const int lp = mt * 8 + (li >> 1);
        const float* Wsrc = (li & 1) ? W_lv : W_mu;
        bf16x8 aM[5], aE[5];
        #pragma unroll
        for (int kb = 0; kb < 5; kb++) {
            bf16x8 f = {}, f2 = {};
            if (kb < 4 || q == 0) {                   // kb==4: c-part (k=128..135), q==0 lanes
                const float* p = Wsrc + lp * 136 + (kb < 4 ? kb * 32 + q * 8 : 128);
                #pragma unroll
                for (int jj = 0; jj < 8; jj++) {
                    float v = p[jj];
                    __bf16 hi = (__bf16)v;
                    f[jj]  = hi;
                    f2[jj] = (__bf16)(v - (float)hi); // residual -> f32-level precision
                }
            }
            aM[kb] = f; aE[kb] = f2;
        }
        #pragma unroll
        for (int jn = 0; jn < 2; jn++) {
            const int nt = (w >> 2) * 2 + jn;         // waves 0-3: nt 0,1; waves 4-7: nt 2,3
            floatx4 acc = zf;
            #pragma unroll
            for (int kb = 0; kb < 4; kb++) {
                bf16x8 hf = *(const bf16x8*)&hA[(nt * 16 + li) * HP + kb * 32 + q * 8];
                acc = MFMA16(aM[kb], hf, acc);
                acc = MFMA16(aE[kb], hf, acc);
            }
            {
                bf16x8 cf = {};
                if (q == 0) cf = *(const bf16x8*)&ctx_s[(nt * 16 + li) * CXP + Ll];
                acc = MFMA16(aM[4], cf, acc);
                acc = MFMA16(aE[4], cf, acc);
            }
            const int b = nt * 16 + li;
            const size_t bg = (size_t)b0 + b;
            const int l0 = mt * 8 + q * 2;
            float mu0 = acc[0] + b_mu[l0],     lv0 = acc[1] + b_lv[l0];
            float mu1 = acc[2] + b_mu[l0 + 1], lv1 = acc[3] + b_lv[l0 + 1];
            float2 ev = *(const float2*)&eps[bg * Ll + l0];
            float z0 = mu0 + ev.x * __expf(0.5f * lv0);
            float z1 = mu1 + ev.y * __expf(0.5f * lv1);
            ctx_s[b * CXP + l0]     = (__bf16)z0;
            ctx_s[b * CXP + l0 + 1] = (__bf16)z1;
            *(float2*)&out[MU_OFF + bg * Ll + l0] = make_float2(mu0, mu1);
            *(float2*)&out[LV_OFF + bg * Ll + l0] = make_float2(lv0, lv1);
        }
    }
    __syncthreads();   // B1: z in ctx_s + dec_tab visible; hA reads done

    // ======= h0 GEMM + decoder t-invariant base GEMM (shared ctx frags) =====
    // aC0/aC1 pre-scaled by -log2e; aC2 by 2log2e; afh (W_fch) unscaled.
    floatx4 h0a[4] = {zf, zf, zf, zf};
    floatx4 base[3][4];
    #pragma unroll
    for (int role = 0; role < 3; role++)
        #pragma unroll
        for (int nt = 0; nt < 4; nt++) base[role][nt] = zf;
    #pragma unroll
    for (int kb2 = 0; kb2 < 2; kb2++) {
        bf16x8 afh, aC0, aC1, aC2;
        #pragma unroll
        for (int jj = 0; jj < 8; jj++) {
            int k = kb2 * 32 + q * 8 + jj;            // ctx k (0..63); valid < 40
            bool ok = (k < 40);
            afh[jj] = ok ? (__bf16)W_fch[(w * 16 + li) * 40 + k]                            : (__bf16)0.f;
            aC0[jj] = ok ? (__bf16)(W_ih_d[(0 * Hh + w * 16 + li) * 104 + Ee + k] * NLOG2E) : (__bf16)0.f;
            aC1[jj] = ok ? (__bf16)(W_ih_d[(1 * Hh + w * 16 + li) * 104 + Ee + k] * NLOG2E) : (__bf16)0.f;
            aC2[jj] = ok ? (__bf16)(W_ih_d[(2 * Hh + w * 16 + li) * 104 + Ee + k] * TLOG2E) : (__bf16)0.f;
        }
        #pragma unroll
        for (int nt = 0; nt < 4; nt++) {
            bf16x8 cf = *(const bf16x8*)&ctx_s[(nt * 16 + li) * CXP + kb2 * 32 + q * 8];
            h0a[nt]     = MFMA16(afh, cf, h0a[nt]);
            base[0][nt] = MFMA16(aC0, cf, base[0][nt]);
            base[1][nt] = MFMA16(aC1, cf, base[1][nt]);
            base[2][nt] = MFMA16(aC2, cf, base[2][nt]);
        }
    }
    // h0 epilogue: C layout == hreg layout -> no LDS round-trip for registers
    #pragma unroll
    for (int nt = 0; nt < 4; nt++) {
        bf16x4 hv;
        #pragma unroll
        for (int r = 0; r < 4; r++) {
            float s = h0a[nt][r] + b_fch[w * 16 + q * 4 + r];
            hreg[nt][r] = s;
            hv[r] = (__bf16)s;
        }
        *(bf16x4*)&hA[(nt * 16 + li) * HP + w * 16 + q * 4] = hv;
    }
    // fold decoder biases into base (scaled); b_hh_n -> C-init vector (scaled)
    floatx4 bhnv;
    #pragma unroll
    for (int r = 0; r < 4; r++) {
        int j = w * 16 + q * 4 + r;
        float br = (b_ih_d[j] + b_hh_d[j]) * NLOG2E;
        float bz = (b_ih_d[Hh + j] + b_hh_d[Hh + j]) * NLOG2E;
        float bi = b_ih_d[2 * Hh + j] * TLOG2E;
        #pragma unroll
        for (int nt = 0; nt < 4; nt++) {
            base[0][nt][r] += br;
            base[1][nt][r] += bz;
            base[2][nt][r] += bi;
        }
        bhnv[r] = b_hh_d[2 * Hh + j] * TLOG2E;
    }
    // decoder W_hh A-frags (pre-scaled)
    #pragma unroll
    for (int role = 0; role < 3; role++) {
        const float sc = (role < 2) ? NLOG2E : TLOG2E;
        #pragma unroll
        for (int kb = 0; kb < 4; kb++) {
            const float* p = W_hh_d + (role * Hh + w * 16 + li) * Hh + kb * 32 + q * 8;
            bf16x8 f;
            #pragma unroll
            for (int jj = 0; jj < 8; jj++) f[jj] = (__bf16)(p[jj] * sc);
            aW[role][kb] = f;
        }
    }
    // W_out frags: wave w -> tile (mt_o = w&1, nt_o = w>>1)
    const int mt_o = w & 1, nt_o = w >> 1;
    bf16x8 aO[4];
    #pragma unroll
    for (int kb = 0; kb < 4; kb++) {
        int row = mt_o * 16 + li;
        bf16x8 f;
        #pragma unroll
        for (int jj = 0; jj < 8; jj++)
            f[jj] = (row < Vv) ? (__bf16)W_out[row * Hh + kb * 32 + q * 8 + jj] : (__bf16)0.f;
        aO[kb] = f;
    }
    float bo[4];
    #pragma unroll
    for (int r = 0; r < 4; r++) {
        int v = mt_o * 16 + q * 4 + r;
        bo[r] = (v < Vv) ? b_out[v] : 0.f;
    }

    __syncthreads();   // B2: h0 in hA visible

    // ========== decoder GRU: 13 steps, 1 barrier each + fused vocab proj ====
    for (int t = 0; t < Tt - 1; t++) {
        const __bf16* rdb = (t & 1) ? hB : hA;
        __bf16*       wrb = (t & 1) ? hA : hB;

        floatx4 acc[3][4];
        #pragma unroll
        for (int nt = 0; nt < 4; nt++) {
            acc[0][nt] = base[0][nt];
            acc[1][nt] = base[1][nt];
            acc[2][nt] = bhnv;                        // h·W_n + b_hh_n (scaled by r)
        }

        bf16x8 hf[4][4];
        #pragma unroll
        for (int nt = 0; nt < 4; nt++)
            #pragma unroll
            for (int kb = 0; kb < 4; kb++)
                hf[nt][kb] = *(const bf16x8*)&rdb[(nt * 16 + li) * HP + kb * 32 + q * 8];
        #pragma unroll
        for (int kb = 0; kb < 4; kb++)
            #pragma unroll
            for (int role = 0; role < 3; role++)
                #pragma unroll
                for (int nt = 0; nt < 4; nt++)
                    acc[role][nt] = MFMA16(aW[role][kb], hf[nt][kb], acc[role][nt]);

        #pragma unroll
        for (int nt = 0; nt < 4; nt++) {
            int bl = nt * 16 + li;
            int tok = x_s[bl * Tt + t];               // dec_in = x[:, :-1]
            const __bf16* tp = &tab_s[tok * TABP + w * 16 + q * 4];
            bf16x4 tR = *(const bf16x4*)(tp);
            bf16x4 tZ = *(const bf16x4*)(tp + Hh);
            bf16x4 tN = *(const bf16x4*)(tp + 2 * Hh);
            bf16x4 hv;
            #pragma unroll
            for (int r = 0; r < 4; r++) {
                float rr = sigm2(acc[0][nt][r] + (float)tR[r]);
                float zz = sigm2(acc[1][nt][r] + (float)tZ[r]);
                float nn = tanh2(base[2][nt][r] + (float)tN[r] + rr * acc[2][nt][r]);
                float h  = nn + zz * (hreg[nt][r] - nn);
                hreg[nt][r] = h;
                hv[r] = (__bf16)h;
            }
            *(bf16x4*)&wrb[bl * HP + w * 16 + q * 4] = hv;
        }
        __syncthreads();                              // h_new (wrb) visible

        // vocab projection: one 16x16 tile per wave, reads wrb (= h after step t)
        bf16x8 of[4];
        #pragma unroll
        for (int kb = 0; kb < 4; kb++)
            of[kb] = *(const bf16x8*)&wrb[(nt_o * 16 + li) * HP + kb * 32 + q * 8];
        floatx4 po = zf;
        #pragma unroll
        for (int kb = 0; kb < 4; kb++)
            po = MFMA16(aO[kb], of[kb], po);
        {
            int vbase = mt_o * 16 + q * 4;
            floatx4 pv;
            #pragma unroll
            for (int r = 0; r < 4; r++) pv[r] = po[r] + bo[r];
            float* op = &out[((size_t)(b0 + nt_o * 16 + li) * 13 + t) * Vv + vbase];
            if (vbase + 4 <= Vv)      __builtin_memcpy(op, &pv, 16);  // single 16B store
            else if (vbase < Vv)      op[0] = pv[0];                  // vbase 24: v=24 only
        }
    }
}

extern "C" void kernel_launch(void* const* d_in, const int* in_sizes, int n_in,
                              void* d_out, int out_size, void* d_ws, size_t ws_size,
                              hipStream_t stream)
{
    const int*   x       = (const int*)d_in[0];
    const float* c       = (const float*)d_in[1];
    const float* eps     = (const float*)d_in[2];
    const float* emb_enc = (const float*)d_in[3];
    const float* W_ih_e  = (const float*)d_in[4];
    const float* W_hh_e  = (const float*)d_in[5];
    const float* b_ih_e  = (const float*)d_in[6];
    const float* b_hh_e  = (const float*)d_in[7];
    const float* W_mu    = (const float*)d_in[8];
    const float* b_mu    = (const float*)d_in[9];
    const float* W_lv    = (const float*)d_in[10];
    const float* b_lv    = (const float*)d_in[11];
    const float* emb_dec = (const float*)d_in[12];
    const float* W_fch   = (const float*)d_in[13];
    const float* b_fch   = (const float*)d_in[14];
    const float* W_ih_d  = (const float*)d_in[15];
    const float* W_hh_d  = (const float*)d_in[16];
    const float* b_ih_d  = (const float*)d_in[17];
    const float* b_hh_d  = (const float*)d_in[18];
    const float* W_out   = (const float*)d_in[19];
    const float* b_out   = (const float*)d_in[20];

    float* ws = (float*)d_ws;
    const int Btot = in_sizes[0] / Tt;

    cvae_tables<<<75, 256, 0, stream>>>(emb_enc, W_ih_e, b_ih_e, b_hh_e, emb_dec, W_ih_d, ws);

    cvae_mfma<<<Btot / 64, 512, 0, stream>>>(
        x, c, eps, W_hh_e, b_hh_e, W_mu, b_mu, W_lv, b_lv,
        W_fch, b_fch, W_ih_d, W_hh_d, b_ih_d, b_hh_d, W_out, b_out,
        ws, (float*)d_out, Btot);
}